// Round 7
// baseline (5495.444 us; speedup 1.0000x reference)
//
#include <hip/hip_runtime.h>

#define T_N   997
#define B_N   64
#define M_N   (B_N * T_N)      // 63808
#define NS_N  256000
#define EPSF  1.1920929e-7f
#define TWOPI_F 6.283185307179586f
#define PI_F    3.14159265358979323846f
#define STG   16               // xg steps staged in LDS per chunk

typedef __attribute__((ext_vector_type(8))) short sv8;
typedef __attribute__((ext_vector_type(4))) short sv4;
typedef __attribute__((ext_vector_type(4))) float fv4;

__device__ __forceinline__ short f2b(float v) {
    union { float f; unsigned u; } x; x.f = v;
    unsigned r = (x.u + 0x7fffu + ((x.u >> 16) & 1u)) >> 16;
    return (short)r;
}
__device__ __forceinline__ float b2f(short v) {
    union { unsigned u; float f; } x; x.u = ((unsigned)(unsigned short)v) << 16; return x.f;
}
__device__ __forceinline__ float sigm(float x)  { return __fdividef(1.f, 1.f + __expf(-x)); }
__device__ __forceinline__ float tanhf_(float x){ return 1.f - __fdividef(2.f, 1.f + __expf(2.f * x)); }

// LDS-only barrier: waits own LDS ops then syncs. No vmcnt drain (global prefetch/
// flush stay in flight), no sched_barrier pinning (m141 trap).
__device__ __forceinline__ void bar_lds() {
    asm volatile("s_waitcnt lgkmcnt(0)\n\ts_barrier" ::: "memory");
}
// Full barrier incl. vmcnt: used once per chunk (stage readiness + flush ordering).
__device__ __forceinline__ void bar_all() {
    asm volatile("s_waitcnt vmcnt(0) lgkmcnt(0)\n\ts_barrier" ::: "memory");
}

// async global->LDS, 16B per lane; LDS dest = wave-uniform base + lane*16
__device__ __forceinline__ void async_ld16(const void* g, void* l) {
    __builtin_amdgcn_global_load_lds(
        (const __attribute__((address_space(1))) unsigned*)g,
        (__attribute__((address_space(3))) unsigned*)l, 16, 0, 0);
}

// ---------------- weight convert (fp32 -> bf16, K padded with zeros) ----------------
__global__ void wcvt_k(const float* __restrict__ src, short* __restrict__ dst, int K, int KP) {
    int n = blockIdx.y;
    int k = blockIdx.x * 256 + threadIdx.x;
    if (k >= KP) return;
    float v = (k < K) ? src[(size_t)n * K + k] : 0.f;
    dst[(size_t)n * KP + k] = f2b(v);
}

// ---------------- 512-pt complex Stockham FFT core (forward, e^{-i}) ----------------
__device__ __forceinline__ void fft512core(float*& ar, float*& ai, float*& br, float*& bi,
                                           const float* twr, const float* twi, int tid) {
    int mm = 1;
    #pragma unroll
    for (int s = 0; s < 9; ++s) {
        __syncthreads();
        int k  = tid & (mm - 1);
        int jm = tid - k;
        float c0r = ar[tid],       c0i = ai[tid];
        float c1r = ar[tid + 256], c1i = ai[tid + 256];
        float wr = twr[jm], wi = twi[jm];
        float dr = c0r - c1r, di = c0i - c1i;
        int o = tid + jm;
        br[o]      = c0r + c1r;         bi[o]      = c0i + c1i;
        br[o + mm] = wr * dr - wi * di; bi[o + mm] = wr * di + wi * dr;
        float* t0 = ar; ar = br; br = t0;
        float* t1 = ai; ai = bi; bi = t1;
        mm <<= 1;
    }
    __syncthreads();
}

// frame + hann window -> packed complex in are/aim; twiddles in twr/twi
__device__ __forceinline__ void pack_frame(const float* __restrict__ xp,
                                           float* are, float* aim, float* twr, float* twi, int tid) {
    float4 xv = ((const float4*)xp)[tid];
    int n0 = tid * 4;
    float w0 = 0.5f - 0.5f * cosf(TWOPI_F * (n0 + 0) * (1.f / 1024.f));
    float w1 = 0.5f - 0.5f * cosf(TWOPI_F * (n0 + 1) * (1.f / 1024.f));
    float w2 = 0.5f - 0.5f * cosf(TWOPI_F * (n0 + 2) * (1.f / 1024.f));
    float w3 = 0.5f - 0.5f * cosf(TWOPI_F * (n0 + 3) * (1.f / 1024.f));
    are[2 * tid]     = xv.x * w0; aim[2 * tid]     = xv.y * w1;
    are[2 * tid + 1] = xv.z * w2; aim[2 * tid + 1] = xv.w * w3;
    float sv, cv;
    sincosf(-TWOPI_F * tid * (1.f / 512.f), &sv, &cv);
    twr[tid] = cv; twi[tid] = sv;
}

// ---------------- forward: frame + hann + rfft(1024) -> mag (bf16, K padded to 544) -------
__global__ __launch_bounds__(256) void fft_fwd_k(const float* __restrict__ x,
                                                 short* __restrict__ mago) {
    __shared__ float are[512], aim[512], bre[512], bim[512], twr[256], twi[256];
    int tid = threadIdx.x;
    int m = blockIdx.x;
    int b = m / T_N, t = m - b * T_N;
    const float* xp = x + (size_t)b * NS_N + (size_t)t * 256;
    pack_frame(xp, are, aim, twr, twi, tid);
    float *par = are, *pai = aim, *pbr = bre, *pbi = bim;
    fft512core(par, pai, pbr, pbi, twr, twi, tid);
    // real-split untwiddle
    int k = tid;
    int km = (512 - k) & 511;
    float zkr = par[k],  zki = pai[k];
    float zmr = par[km], zmi = pai[km];
    float q2r = 0.f, q2i = 0.f;
    if (k == 0) { q2r = par[256]; q2i = -pai[256]; }
    float xer = 0.5f * (zkr + zmr), xei = 0.5f * (zki - zmi);
    float dr  = 0.5f * (zkr - zmr), di  = 0.5f * (zki + zmi);
    float xor_ = di, xoi = -dr;                    // Xo = -i*d
    float s1, c1;
    sincosf(-PI_F * k * (1.f / 512.f), &s1, &c1);  // e^{-2*pi*i*k/1024}
    float txr = c1 * xor_ - s1 * xoi;
    float txi = c1 * xoi + s1 * xor_;
    float Xkr = xer + txr, Xki = xei + txi;        // X[k]
    float Xmr = xer - txr, Xmi = txi - xei;        // X[512-k] (k=0 -> bin 512)
    size_t mb = (size_t)m * 544;
    float mgk = sqrtf(fmaxf(Xkr * Xkr + Xki * Xki, EPSF));
    float mgm = sqrtf(fmaxf(Xmr * Xmr + Xmi * Xmi, EPSF));
    mago[mb + k]       = f2b(mgk);
    mago[mb + 512 - k] = f2b(mgm);
    if (k == 0) {
        float mg2 = sqrtf(fmaxf(q2r * q2r + q2i * q2i, EPSF));
        mago[mb + 256] = f2b(mg2);
    }
    if (tid >= 1 && tid <= 31) mago[mb + 512 + tid] = 0;  // zero-pad cols 513..543
}

// ---------------- fused: recompute fwd FFT, apply mask*mag*e^{i phase}, irfft -> y1 bf16 ---
__global__ __launch_bounds__(256) void ifft_k(const float* __restrict__ x,
                                              const short* __restrict__ mk,
                                              short* __restrict__ y1) {
    __shared__ float are[512], aim[512], bre[512], bim[512], twr[256], twi[256];
    int tid = threadIdx.x;
    int m = blockIdx.x;
    int b = m / T_N, t = m - b * T_N;
    const float* xp = x + (size_t)b * NS_N + (size_t)t * 256;
    pack_frame(xp, are, aim, twr, twi, tid);
    float *par = are, *pai = aim, *pbr = bre, *pbi = bim;
    fft512core(par, pai, pbr, pbi, twr, twi, tid);
    int k = tid;
    int km = (512 - k) & 511;
    float zkr = par[k],  zki = pai[k];
    float zmr = par[km], zmi = pai[km];
    float q2r = 0.f, q2i = 0.f;
    if (k == 0) { q2r = par[256]; q2i = -pai[256]; }
    float xer = 0.5f * (zkr + zmr), xei = 0.5f * (zki - zmi);
    float dr  = 0.5f * (zkr - zmr), di  = 0.5f * (zki + zmi);
    float xor_ = di, xoi = -dr;
    float s1, c1;
    sincosf(-PI_F * k * (1.f / 512.f), &s1, &c1);
    float txr = c1 * xor_ - s1 * xoi;
    float txi = c1 * xoi + s1 * xor_;
    float Xkr = xer + txr, Xki = xei + txi;        // X[k]
    float Xmr = xer - txr, Xmi = txi - xei;        // X[512-k]
    size_t base = (size_t)m * 513;
    auto mkS = [&](int bin, float r, float i2, bool dropim, float& sr, float& si) {
        float mv = b2f(mk[base + bin]);
        float pr = r + EPSF, pi = i2 + EPSF;
        float den = sqrtf(pr * pr + pi * pi);
        float mg  = sqrtf(fmaxf(r * r + i2 * i2, EPSF));
        float amp = mv * mg * __fdividef(1.f, fmaxf(den, 1e-30f));
        sr = amp * pr; si = dropim ? 0.f : amp * pi;
    };
    float skr, ski, smr, smi;
    if (k == 0) { mkS(0, Xkr, Xki, true, skr, ski);  mkS(512, Xmr, Xmi, true, smr, smi); }
    else        { mkS(k, Xkr, Xki, false, skr, ski); mkS(512 - k, Xmr, Xmi, false, smr, smi); }
    float xe2r = 0.5f * (skr + smr), xe2i = 0.5f * (ski - smi);
    float d2r  = 0.5f * (skr - smr), d2i  = 0.5f * (ski + smi);
    float s2, c2;
    sincosf(PI_F * k * (1.f / 512.f), &s2, &c2);   // e^{+2*pi*i*k/1024}
    float o2r = c2 * d2r - s2 * d2i;
    float o2i = c2 * d2i + s2 * d2r;
    are[k] = xe2r - o2i; aim[k] = -(xe2i + o2r);
    if (k > 0) { are[512 - k] = xe2r + o2i; aim[512 - k] = xe2i - o2r; }
    else {
        float s6r, s6i; mkS(256, q2r, q2i, false, s6r, s6i);
        are[256] = s6r; aim[256] = s6i;            // conj(Z'[256]) = S256
    }
    float *p2r = are, *p2i = aim, *p2br = bre, *p2bi = bim;
    fft512core(p2r, p2i, p2br, p2bi, twr, twi, tid);
    float sc = 1.f / 512.f;
    int n = 2 * tid;
    sv4 o4;
    o4[0] = f2b(p2r[n] * sc);      o4[1] = f2b(-p2i[n] * sc);
    o4[2] = f2b(p2r[n + 1] * sc);  o4[3] = f2b(-p2i[n + 1] * sc);
    *(sv4*)(y1 + (size_t)m * 1024 + 4 * tid) = o4;
}

// ---------------- bf16 MFMA GEMM: out = act(A @ W^T + b1 + b2) [* mul], bf16 out ----------
// ACT: 0 = none, 1 = sigmoid, 2 = sigmoid then * mul(bf16)
// PERM: output column permutation gate-major -> j-major: col G stored at (G&127)*4 + (G>>7)
template<int ACT, bool PERM>
__global__ __launch_bounds__(256) void gemm_k(
    const short* __restrict__ A, int lda,
    const short* __restrict__ W, int ldw,
    short* __restrict__ outB, int ldc,
    int Mr, int Nc, int Kp,
    const float* __restrict__ b1, const float* __restrict__ b2,
    const short* __restrict__ mul, int ldm)
{
    __shared__ short As[128 * 32];
    __shared__ short Bs[128 * 32];
    int tid = threadIdx.x;
    int m0 = blockIdx.x * 128, n0 = blockIdx.y * 128;
    int w = tid >> 6, lane = tid & 63, llo = lane & 15, lhi = lane >> 4;
    int wm = w & 1, wn = w >> 1;
    fv4 acc[4][4] = {};
    int nK = Kp >> 5;
    for (int kb = 0; kb < nK; ++kb) {
        __syncthreads();
        #pragma unroll
        for (int i = 0; i < 2; ++i) {
            int idx = tid + i * 256;
            int row = idx >> 2, c = idx & 3;
            int ra = m0 + row; if (ra > Mr - 1) ra = Mr - 1;
            sv8 va = *(const sv8*)(A + (size_t)ra * lda + kb * 32 + c * 8);
            *(sv8*)&As[idx * 8] = va;
            int rb = n0 + row; if (rb > Nc - 1) rb = Nc - 1;
            sv8 vb = *(const sv8*)(W + (size_t)rb * ldw + kb * 32 + c * 8);
            *(sv8*)&Bs[idx * 8] = vb;
        }
        __syncthreads();
        sv8 af[4], bfr[4];
        #pragma unroll
        for (int mt = 0; mt < 4; ++mt) af[mt]  = *(const sv8*)&As[(wm * 64 + mt * 16 + llo) * 32 + lhi * 8];
        #pragma unroll
        for (int nt = 0; nt < 4; ++nt) bfr[nt] = *(const sv8*)&Bs[(wn * 64 + nt * 16 + llo) * 32 + lhi * 8];
        #pragma unroll
        for (int mt = 0; mt < 4; ++mt)
            #pragma unroll
            for (int nt = 0; nt < 4; ++nt)
                acc[mt][nt] = __builtin_amdgcn_mfma_f32_16x16x32_bf16(af[mt], bfr[nt], acc[mt][nt], 0, 0, 0);
    }
    #pragma unroll
    for (int nt = 0; nt < 4; ++nt) {
        int col = n0 + wn * 64 + nt * 16 + llo;
        if (col >= Nc) continue;
        float bv = 0.f;
        if (b1) bv += b1[col];
        if (b2) bv += b2[col];
        int oc = PERM ? ((col & 127) * 4 + (col >> 7)) : col;
        #pragma unroll
        for (int mt = 0; mt < 4; ++mt) {
            #pragma unroll
            for (int r = 0; r < 4; ++r) {
                int row = m0 + wm * 64 + mt * 16 + lhi * 4 + r;
                if (row >= Mr) continue;
                float v = acc[mt][nt][r] + bv;
                if constexpr (ACT >= 1) v = sigm(v);
                if constexpr (ACT == 2) v *= b2f(mul[(size_t)row * ldm + col]);
                outB[(size_t)row * ldc + oc] = f2b(v);
            }
        }
    }
}

// ---------------- fused double-LSTM scan: both layers of one sep-block per step -----------
// 2 batch / block, 4 waves. Wave w owns j-range [w*32, w*32+32): 8 MFMA tiles per matvec.
// Three matvecs per step: Whh1@h1(t-1) -> gates1 -> h1(t); then Wih2@h1(t) + Whh2@h2(t-1)
// -> (+bias2) gates2 -> h2(t). All 3 weight sets as B-frags in VGPRs (384 regs).
// Gate phases run on all 256 threads (thread = one (b,j) cell). 4 LDS-only barriers/step.
// xg1 staged via global_load_lds double-buffer; only H2 goes to global (H1 never leaves).
__global__ __launch_bounds__(256, 1) void fscan_k(
    const short* __restrict__ xg1,
    const float* __restrict__ Whh1, const float* __restrict__ Wih2,
    const float* __restrict__ Whh2,
    const float* __restrict__ bih2, const float* __restrict__ bhh2,
    short* __restrict__ Hout)
{
    __shared__ short stage[2][2 * STG * 512];  // xg1: [buf][b*16+tr][j*4+g], 32 KB each
    __shared__ short hl1[16 * 132];            // h1 (A-frag layout, rows 0,1 = batches)
    __shared__ short hl2[16 * 132];            // h2
    __shared__ short hbuf[STG * 256];          // h2 history: [tr][b][j]
    __shared__ float gbuf1[2 * 128 * 4];       // lstm1 preacts: [b][j][4]
    __shared__ float gbuf2[2 * 128 * 4];       // lstm2 recurrent+input preacts
    __shared__ float bias2s[128 * 4];          // bih2+bhh2, j-major
    int tid = threadIdx.x;
    int lane = tid & 63, w = tid >> 6, llo = lane & 15, lhi = lane >> 4;
    // weight fragments: [g][jj][kc], lane holds W[g*128 + w*32 + jj*16 + llo][kc*32+lhi*8 ..+8]
    sv8 w1r[4][2][4], wir[4][2][4], w2r[4][2][4];
    #pragma unroll
    for (int g = 0; g < 4; ++g)
        #pragma unroll
        for (int jj = 0; jj < 2; ++jj) {
            int gate = g * 128 + w * 32 + jj * 16 + llo;
            #pragma unroll
            for (int kc = 0; kc < 4; ++kc) {
                size_t o = (size_t)gate * 128 + kc * 32 + lhi * 8;
                sv8 v1, v2, v3;
                #pragma unroll
                for (int e = 0; e < 8; ++e) {
                    v1[e] = f2b(Whh1[o + e]);
                    v2[e] = f2b(Wih2[o + e]);
                    v3[e] = f2b(Whh2[o + e]);
                }
                w1r[g][jj][kc] = v1; wir[g][jj][kc] = v2; w2r[g][jj][kc] = v3;
            }
        }
    for (int i = tid; i < 16 * 132; i += 256) { hl1[i] = 0; hl2[i] = 0; }
    if (tid < 128) {
        #pragma unroll
        for (int g = 0; g < 4; ++g)
            bias2s[tid * 4 + g] = bih2[g * 128 + tid] + bhh2[g * 128 + tid];
    }
    int b0 = blockIdx.x * 2;
    const short* xgb = xg1 + ((size_t)b0 * T_N) * 512;
    short* hob = Hout + ((size_t)b0 * T_N) * 128;
    float c1 = 0.f, c2 = 0.f;                  // cell states: thread (b=tid>>7, j=tid&127)
    int gb = tid >> 7, gj = tid & 127;
    auto prefetch = [&](int t0n, short* buf) {
        #pragma unroll
        for (int it = 0; it < 8; ++it) {
            int row = w * 8 + it;              // row = b*16 + tr
            int bb = row >> 4;
            int tg = t0n + (row & 15); if (tg > T_N - 1) tg = T_N - 1;
            const short* src = xgb + ((size_t)bb * T_N + tg) * 512 + lane * 8;
            async_ld16(src, buf + row * 512);
        }
    };
    auto flushf = [&](int tbase, int ns2) {    // hbuf -> Hout, coalesced b128 (512 x 16B)
        #pragma unroll
        for (int half = 0; half < 2; ++half) {
            int r = half * 256 + tid;
            int tr2 = r >> 5, fb = (r >> 4) & 1, j8 = r & 15;
            if (tr2 < ns2) {
                sv8 v = *(const sv8*)&hbuf[r * 8];
                *(sv8*)(hob + ((size_t)fb * T_N + tbase + tr2) * 128 + j8 * 8) = v;
            }
        }
    };
    prefetch(0, stage[0]);
    __syncthreads();                           // inits visible + stage[0] ready (vm drained)
    for (int t0 = 0; t0 < T_N; t0 += STG) {
        int cb = (t0 / STG) & 1;
        short* buf = stage[cb];
        if (t0 + STG < T_N) prefetch(t0 + STG, stage[cb ^ 1]);
        int ns = (T_N - t0 < STG) ? (T_N - t0) : STG;
        for (int tr = 0; tr < ns; ++tr) {
            // ---- phase A: LSTM1 recurrent matvec h1(t-1) @ Whh1^T ----
            sv8 af[4];
            #pragma unroll
            for (int kc = 0; kc < 4; ++kc)
                af[kc] = *(const sv8*)&hl1[llo * 132 + kc * 32 + lhi * 8];
            {
                fv4 a1[4][2];
                #pragma unroll
                for (int g = 0; g < 4; ++g)
                    #pragma unroll
                    for (int jj = 0; jj < 2; ++jj) {
                        fv4 a = {0.f, 0.f, 0.f, 0.f};
                        #pragma unroll
                        for (int kc = 0; kc < 4; ++kc)
                            a = __builtin_amdgcn_mfma_f32_16x16x32_bf16(af[kc], w1r[g][jj][kc], a, 0, 0, 0);
                        a1[g][jj] = a;
                    }
                if (lhi == 0) {
                    #pragma unroll
                    for (int jj = 0; jj < 2; ++jj) {
                        int j = w * 32 + jj * 16 + llo;
                        #pragma unroll
                        for (int r = 0; r < 2; ++r) {
                            fv4 pk = { a1[0][jj][r], a1[1][jj][r], a1[2][jj][r], a1[3][jj][r] };
                            *(fv4*)&gbuf1[(r * 128 + j) * 4] = pk;
                        }
                    }
                }
            }
            bar_lds();
            // ---- phase B: LSTM1 gates (all 256 threads) ----
            {
                fv4 pre = *(const fv4*)&gbuf1[(gb * 128 + gj) * 4];
                sv4 xs = *(const sv4*)&buf[(gb * 16 + tr) * 512 + gj * 4];
                float gi = pre[0] + b2f(xs[0]);
                float gf = pre[1] + b2f(xs[1]);
                float gg = pre[2] + b2f(xs[2]);
                float go = pre[3] + b2f(xs[3]);
                float cn = sigm(gf) * c1 + sigm(gi) * tanhf_(gg);
                float hn = sigm(go) * tanhf_(cn);
                c1 = cn;
                hl1[gb * 132 + gj] = f2b(hn);
            }
            bar_lds();
            // ---- phase A2: Wih2 @ h1(t) + Whh2 @ h2(t-1) ----
            {
                fv4 a2[4][2];
                #pragma unroll
                for (int kc = 0; kc < 4; ++kc)
                    af[kc] = *(const sv8*)&hl1[llo * 132 + kc * 32 + lhi * 8];
                #pragma unroll
                for (int g = 0; g < 4; ++g)
                    #pragma unroll
                    for (int jj = 0; jj < 2; ++jj) {
                        fv4 a = {0.f, 0.f, 0.f, 0.f};
                        #pragma unroll
                        for (int kc = 0; kc < 4; ++kc)
                            a = __builtin_amdgcn_mfma_f32_16x16x32_bf16(af[kc], wir[g][jj][kc], a, 0, 0, 0);
                        a2[g][jj] = a;
                    }
                #pragma unroll
                for (int kc = 0; kc < 4; ++kc)
                    af[kc] = *(const sv8*)&hl2[llo * 132 + kc * 32 + lhi * 8];
                #pragma unroll
                for (int g = 0; g < 4; ++g)
                    #pragma unroll
                    for (int jj = 0; jj < 2; ++jj) {
                        fv4 a = a2[g][jj];
                        #pragma unroll
                        for (int kc = 0; kc < 4; ++kc)
                            a = __builtin_amdgcn_mfma_f32_16x16x32_bf16(af[kc], w2r[g][jj][kc], a, 0, 0, 0);
                        a2[g][jj] = a;
                    }
                if (lhi == 0) {
                    #pragma unroll
                    for (int jj = 0; jj < 2; ++jj) {
                        int j = w * 32 + jj * 16 + llo;
                        #pragma unroll
                        for (int r = 0; r < 2; ++r) {
                            fv4 pk = { a2[0][jj][r], a2[1][jj][r], a2[2][jj][r], a2[3][jj][r] };
                            *(fv4*)&gbuf2[(r * 128 + j) * 4] = pk;
                        }
                    }
                }
            }
            bar_lds();
            // ---- phase C: LSTM2 gates ----
            {
                fv4 p2 = *(const fv4*)&gbuf2[(gb * 128 + gj) * 4];
                fv4 bz = *(const fv4*)&bias2s[gj * 4];
                float gi = p2[0] + bz[0];
                float gf = p2[1] + bz[1];
                float gg = p2[2] + bz[2];
                float go = p2[3] + bz[3];
                float cn = sigm(gf) * c2 + sigm(gi) * tanhf_(gg);
                float hn = sigm(go) * tanhf_(cn);
                c2 = cn;
                short hb = f2b(hn);
                hl2[gb * 132 + gj] = hb;
                hbuf[tr * 256 + gb * 128 + gj] = hb;
            }
            bar_lds();
        }
        flushf(t0, ns);
        bar_all();                             // next chunk's stage ready; flush ordered
    }
}

// ---------------- instance layer norm over last dim (256), bf16 in/out ----------------
__global__ __launch_bounds__(256) void iln_k(const short* __restrict__ enc,
                                             const float* __restrict__ gamma, const float* __restrict__ beta,
                                             short* __restrict__ out, int Mr) {
    int tid = threadIdx.x;
    int lane = tid & 63;
    int row = blockIdx.x * 4 + (tid >> 6);
    if (row >= Mr) return;
    sv4 v4 = *(const sv4*)(enc + (size_t)row * 256 + lane * 4);
    float vx = b2f(v4[0]), vy = b2f(v4[1]), vz = b2f(v4[2]), vw = b2f(v4[3]);
    float s = vx + vy + vz + vw;
    #pragma unroll
    for (int o = 32; o; o >>= 1) s += __shfl_xor(s, o);
    float mean = s * (1.f / 256.f);
    float dx = vx - mean, dy = vy - mean, dz = vz - mean, dw = vw - mean;
    float q = dx * dx + dy * dy + dz * dz + dw * dw;
    #pragma unroll
    for (int o = 32; o; o >>= 1) q += __shfl_xor(q, o);
    float rs = rsqrtf(q * (1.f / 256.f) + 1e-7f);
    float4 g = ((const float4*)gamma)[lane];
    float4 b = ((const float4*)beta)[lane];
    sv4 o4;
    o4[0] = f2b(dx * rs * g.x + b.x);
    o4[1] = f2b(dy * rs * g.y + b.y);
    o4[2] = f2b(dz * rs * g.z + b.z);
    o4[3] = f2b(dw * rs * g.w + b.w);
    *(sv4*)(out + (size_t)row * 256 + lane * 4) = o4;
}

// ---------------- overlap-add (dec bf16 -> out fp32) ----------------
__global__ __launch_bounds__(256) void ola_k(const short* __restrict__ dec, float* __restrict__ out, int n) {
    int gid = blockIdx.x * 256 + threadIdx.x;
    if (gid >= n) return;
    int b = gid / NS_N;
    int s = gid - b * NS_N;
    int thi = s >> 8; if (thi > T_N - 1) thi = T_N - 1;
    int tlo = (s >= 1023) ? ((s - 1023 + 255) >> 8) : 0;
    float acc = 0.f;
    for (int t2 = tlo; t2 <= thi; ++t2)
        acc += b2f(dec[(size_t)(b * T_N + t2) * 1024 + (s - (t2 << 8))]);
    out[gid] = acc;
}

extern "C" void kernel_launch(void* const* d_in, const int* in_sizes, int n_in,
                              void* d_out, int out_size, void* d_ws, size_t ws_size,
                              hipStream_t stream) {
    (void)in_sizes; (void)n_in; (void)out_size;
    const float* x      = (const float*)d_in[0];
    const float* s1Wih1 = (const float*)d_in[3];
    const float* s1Whh1 = (const float*)d_in[4];
    const float* s1bih1 = (const float*)d_in[5];
    const float* s1bhh1 = (const float*)d_in[6];
    const float* s1Wih2 = (const float*)d_in[7];
    const float* s1Whh2 = (const float*)d_in[8];
    const float* s1bih2 = (const float*)d_in[9];
    const float* s1bhh2 = (const float*)d_in[10];
    const float* s1Wd   = (const float*)d_in[11];
    const float* s1bd   = (const float*)d_in[12];
    const float* s2Wih1 = (const float*)d_in[13];
    const float* s2Whh1 = (const float*)d_in[14];
    const float* s2bih1 = (const float*)d_in[15];
    const float* s2bhh1 = (const float*)d_in[16];
    const float* s2Wih2 = (const float*)d_in[17];
    const float* s2Whh2 = (const float*)d_in[18];
    const float* s2bih2 = (const float*)d_in[19];
    const float* s2bhh2 = (const float*)d_in[20];
    const float* s2Wd   = (const float*)d_in[21];
    const float* s2bd   = (const float*)d_in[22];
    const float* encW   = (const float*)d_in[23];
    const float* decW   = (const float*)d_in[24];
    const float* gamma  = (const float*)d_in[25];
    const float* beta   = (const float*)d_in[26];
    float* out = (float*)d_out;

    char* ws = (char*)d_ws;
    size_t off = 0;
    auto alloc = [&](size_t bytes) -> void* {
        size_t o = (off + 255) & ~(size_t)255;
        off = o + bytes;
        return (void*)(ws + o);
    };
    // persistent weights (converted once per launch)
    short* Wih1p = (short*)alloc((size_t)512 * 544 * 2);
    short* Wd1   = (short*)alloc((size_t)513 * 128 * 2);
    short* Wih1b = (short*)alloc((size_t)512 * 256 * 2);
    short* Wd2   = (short*)alloc((size_t)256 * 128 * 2);
    short* encWb = (short*)alloc((size_t)256 * 1024 * 2);
    short* decWb = (short*)alloc((size_t)1024 * 256 * 2);
    size_t woff = off;

    // choose the largest even batch-chunk MB whose buffers fit ws_size
    int MB = 0;
    for (int mb = 64; mb >= 2; mb -= 2) {
        size_t Mc = (size_t)mb * T_N;
        size_t tot = woff;
        auto add = [&](size_t bts) { tot = ((tot + 255) & ~(size_t)255) + bts; };
        add(Mc * 1056 * 2);  // R1 (mag 544 | xg 512; y1/dec alias)
        add(Mc * 128 * 2);   // H2
        add(Mc * 513 * 2);   // Rm (mask1; encn/adec alias)
        add(Mc * 256 * 2);   // encb
        if (tot <= ws_size) { MB = mb; break; }
    }
    if (MB == 0) return;  // hopeless: < ~10 MB of scratch
    size_t McCap = (size_t)MB * T_N;
    short* R1   = (short*)alloc(McCap * 1056 * 2);
    short* H2   = (short*)alloc(McCap * 128 * 2);
    short* Rm   = (short*)alloc(McCap * 513 * 2);
    short* encb = (short*)alloc(McCap * 256 * 2);

    // weight conversions (fp32 -> bf16, K zero-padded)
    wcvt_k<<<dim3(3, 512),  256, 0, stream>>>(s1Wih1, Wih1p, 513, 544);
    wcvt_k<<<dim3(1, 513),  256, 0, stream>>>(s1Wd,   Wd1,   128, 128);
    wcvt_k<<<dim3(1, 512),  256, 0, stream>>>(s2Wih1, Wih1b, 256, 256);
    wcvt_k<<<dim3(1, 256),  256, 0, stream>>>(s2Wd,   Wd2,   128, 128);
    wcvt_k<<<dim3(4, 256),  256, 0, stream>>>(encW,   encWb, 1024, 1024);
    wcvt_k<<<dim3(1, 1024), 256, 0, stream>>>(decW,   decWb, 256, 256);

    for (int cs = 0; cs < B_N; cs += MB) {
        int mb = (B_N - cs < MB) ? (B_N - cs) : MB;
        size_t mc = (size_t)mb * T_N;
        int gx = (int)((mc + 127) / 128);
        const float* xc = x + (size_t)cs * NS_N;
        float* outc = out + (size_t)cs * NS_N;
        short* mag  = R1;
        short* xg   = R1 + mc * 544;
        short* y1   = R1;             // alias (mag+xg dead)
        short* decb = R1;             // alias (y1/xg dead)
        short* mask1 = Rm;
        short* encn  = Rm;            // alias (mask1 dead)
        short* adec  = Rm + mc * 256; // alias (mask1 dead)

        // STFT magnitudes
        fft_fwd_k<<<(int)mc, 256, 0, stream>>>(xc, mag);
        // separation block 1: input gemm (j-major) + fused double-LSTM scan
        gemm_k<0, true><<<dim3(gx, 4), 256, 0, stream>>>(mag, 544, Wih1p, 544, xg, 512, (int)mc, 512, 544, s1bih1, s1bhh1, nullptr, 0);
        fscan_k<<<mb / 2, 256, 0, stream>>>(xg, s1Whh1, s1Wih2, s1Whh2, s1bih2, s1bhh2, H2);
        gemm_k<1, false><<<dim3(gx, 5), 256, 0, stream>>>(H2, 128, Wd1, 128, mask1, 513, (int)mc, 513, 128, s1bd, nullptr, nullptr, 0);
        // masked iSTFT + encoder + norm
        ifft_k<<<(int)mc, 256, 0, stream>>>(xc, mask1, y1);
        gemm_k<0, false><<<dim3(gx, 2), 256, 0, stream>>>(y1, 1024, encWb, 1024, encb, 256, (int)mc, 256, 1024, nullptr, nullptr, nullptr, 0);
        iln_k<<<(int)((mc + 3) / 4), 256, 0, stream>>>(encb, gamma, beta, encn, (int)mc);
        // separation block 2
        gemm_k<0, true><<<dim3(gx, 4), 256, 0, stream>>>(encn, 256, Wih1b, 256, xg, 512, (int)mc, 512, 256, s2bih1, s2bhh1, nullptr, 0);
        fscan_k<<<mb / 2, 256, 0, stream>>>(xg, s2Whh1, s2Wih2, s2Whh2, s2bih2, s2bhh2, H2);
        gemm_k<2, false><<<dim3(gx, 2), 256, 0, stream>>>(H2, 128, Wd2, 128, adec, 256, (int)mc, 256, 128, s2bd, nullptr, encb, 256);
        // decoder + overlap-add
        gemm_k<0, false><<<dim3(gx, 8), 256, 0, stream>>>(adec, 256, decWb, 256, decb, 1024, (int)mc, 1024, 256, nullptr, nullptr, nullptr, 0);
        ola_k<<<mb * 1000, 256, 0, stream>>>(decb, outc, mb * NS_N);
    }
}

// Round 8
// 4049.435 us; speedup vs baseline: 1.3571x; 1.3571x over previous
//
#include <hip/hip_runtime.h>

#define T_N   997
#define B_N   64
#define M_N   (B_N * T_N)      // 63808
#define NS_N  256000
#define EPSF  1.1920929e-7f
#define TWOPI_F 6.283185307179586f
#define PI_F    3.14159265358979323846f
#define STG   16               // xg steps staged in LDS per chunk

typedef __attribute__((ext_vector_type(8))) short sv8;
typedef __attribute__((ext_vector_type(4))) short sv4;
typedef __attribute__((ext_vector_type(4))) float fv4;

__device__ __forceinline__ short f2b(float v) {
    union { float f; unsigned u; } x; x.f = v;
    unsigned r = (x.u + 0x7fffu + ((x.u >> 16) & 1u)) >> 16;
    return (short)r;
}
__device__ __forceinline__ float b2f(short v) {
    union { unsigned u; float f; } x; x.u = ((unsigned)(unsigned short)v) << 16; return x.f;
}
__device__ __forceinline__ float sigm(float x)  { return __fdividef(1.f, 1.f + __expf(-x)); }
__device__ __forceinline__ float tanhf_(float x){ return 1.f - __fdividef(2.f, 1.f + __expf(2.f * x)); }

// LDS-only barrier: waits own LDS ops then syncs. No vmcnt drain, no sched pinning.
__device__ __forceinline__ void bar_lds() {
    asm volatile("s_waitcnt lgkmcnt(0)\n\ts_barrier" ::: "memory");
}
// Full barrier incl. vmcnt: once per chunk (stage readiness + flush ordering).
__device__ __forceinline__ void bar_all() {
    asm volatile("s_waitcnt vmcnt(0) lgkmcnt(0)\n\ts_barrier" ::: "memory");
}
// wave-local LDS visibility (producer lanes -> consumer lanes, same wave)
__device__ __forceinline__ void wave_lds_fence() {
    asm volatile("s_waitcnt lgkmcnt(0)" ::: "memory");
}

// async global->LDS, 16B per lane; LDS dest = wave-uniform base + lane*16
__device__ __forceinline__ void async_ld16(const void* g, void* l) {
    __builtin_amdgcn_global_load_lds(
        (const __attribute__((address_space(1))) unsigned*)g,
        (__attribute__((address_space(3))) unsigned*)l, 16, 0, 0);
}

// ---------------- weight convert (fp32 -> bf16, K padded with zeros) ----------------
__global__ void wcvt_k(const float* __restrict__ src, short* __restrict__ dst, int K, int KP) {
    int n = blockIdx.y;
    int k = blockIdx.x * 256 + threadIdx.x;
    if (k >= KP) return;
    float v = (k < K) ? src[(size_t)n * K + k] : 0.f;
    dst[(size_t)n * KP + k] = f2b(v);
}

// ---------------- 512-pt complex Stockham FFT core (forward, e^{-i}) ----------------
__device__ __forceinline__ void fft512core(float*& ar, float*& ai, float*& br, float*& bi,
                                           const float* twr, const float* twi, int tid) {
    int mm = 1;
    #pragma unroll
    for (int s = 0; s < 9; ++s) {
        __syncthreads();
        int k  = tid & (mm - 1);
        int jm = tid - k;
        float c0r = ar[tid],       c0i = ai[tid];
        float c1r = ar[tid + 256], c1i = ai[tid + 256];
        float wr = twr[jm], wi = twi[jm];
        float dr = c0r - c1r, di = c0i - c1i;
        int o = tid + jm;
        br[o]      = c0r + c1r;         bi[o]      = c0i + c1i;
        br[o + mm] = wr * dr - wi * di; bi[o + mm] = wr * di + wi * dr;
        float* t0 = ar; ar = br; br = t0;
        float* t1 = ai; ai = bi; bi = t1;
        mm <<= 1;
    }
    __syncthreads();
}

// frame + hann window -> packed complex in are/aim; twiddles in twr/twi
__device__ __forceinline__ void pack_frame(const float* __restrict__ xp,
                                           float* are, float* aim, float* twr, float* twi, int tid) {
    float4 xv = ((const float4*)xp)[tid];
    int n0 = tid * 4;
    float w0 = 0.5f - 0.5f * cosf(TWOPI_F * (n0 + 0) * (1.f / 1024.f));
    float w1 = 0.5f - 0.5f * cosf(TWOPI_F * (n0 + 1) * (1.f / 1024.f));
    float w2 = 0.5f - 0.5f * cosf(TWOPI_F * (n0 + 2) * (1.f / 1024.f));
    float w3 = 0.5f - 0.5f * cosf(TWOPI_F * (n0 + 3) * (1.f / 1024.f));
    are[2 * tid]     = xv.x * w0; aim[2 * tid]     = xv.y * w1;
    are[2 * tid + 1] = xv.z * w2; aim[2 * tid + 1] = xv.w * w3;
    float sv, cv;
    sincosf(-TWOPI_F * tid * (1.f / 512.f), &sv, &cv);
    twr[tid] = cv; twi[tid] = sv;
}

// ---------------- forward: frame + hann + rfft(1024) -> mag (bf16, K padded to 544) -------
__global__ __launch_bounds__(256) void fft_fwd_k(const float* __restrict__ x,
                                                 short* __restrict__ mago) {
    __shared__ float are[512], aim[512], bre[512], bim[512], twr[256], twi[256];
    int tid = threadIdx.x;
    int m = blockIdx.x;
    int b = m / T_N, t = m - b * T_N;
    const float* xp = x + (size_t)b * NS_N + (size_t)t * 256;
    pack_frame(xp, are, aim, twr, twi, tid);
    float *par = are, *pai = aim, *pbr = bre, *pbi = bim;
    fft512core(par, pai, pbr, pbi, twr, twi, tid);
    // real-split untwiddle
    int k = tid;
    int km = (512 - k) & 511;
    float zkr = par[k],  zki = pai[k];
    float zmr = par[km], zmi = pai[km];
    float q2r = 0.f, q2i = 0.f;
    if (k == 0) { q2r = par[256]; q2i = -pai[256]; }
    float xer = 0.5f * (zkr + zmr), xei = 0.5f * (zki - zmi);
    float dr  = 0.5f * (zkr - zmr), di  = 0.5f * (zki + zmi);
    float xor_ = di, xoi = -dr;                    // Xo = -i*d
    float s1, c1;
    sincosf(-PI_F * k * (1.f / 512.f), &s1, &c1);  // e^{-2*pi*i*k/1024}
    float txr = c1 * xor_ - s1 * xoi;
    float txi = c1 * xoi + s1 * xor_;
    float Xkr = xer + txr, Xki = xei + txi;        // X[k]
    float Xmr = xer - txr, Xmi = txi - xei;        // X[512-k] (k=0 -> bin 512)
    size_t mb = (size_t)m * 544;
    float mgk = sqrtf(fmaxf(Xkr * Xkr + Xki * Xki, EPSF));
    float mgm = sqrtf(fmaxf(Xmr * Xmr + Xmi * Xmi, EPSF));
    mago[mb + k]       = f2b(mgk);
    mago[mb + 512 - k] = f2b(mgm);
    if (k == 0) {
        float mg2 = sqrtf(fmaxf(q2r * q2r + q2i * q2i, EPSF));
        mago[mb + 256] = f2b(mg2);
    }
    if (tid >= 1 && tid <= 31) mago[mb + 512 + tid] = 0;  // zero-pad cols 513..543
}

// ---------------- fused: recompute fwd FFT, apply mask*mag*e^{i phase}, irfft -> y1 bf16 ---
__global__ __launch_bounds__(256) void ifft_k(const float* __restrict__ x,
                                              const short* __restrict__ mk,
                                              short* __restrict__ y1) {
    __shared__ float are[512], aim[512], bre[512], bim[512], twr[256], twi[256];
    int tid = threadIdx.x;
    int m = blockIdx.x;
    int b = m / T_N, t = m - b * T_N;
    const float* xp = x + (size_t)b * NS_N + (size_t)t * 256;
    pack_frame(xp, are, aim, twr, twi, tid);
    float *par = are, *pai = aim, *pbr = bre, *pbi = bim;
    fft512core(par, pai, pbr, pbi, twr, twi, tid);
    int k = tid;
    int km = (512 - k) & 511;
    float zkr = par[k],  zki = pai[k];
    float zmr = par[km], zmi = pai[km];
    float q2r = 0.f, q2i = 0.f;
    if (k == 0) { q2r = par[256]; q2i = -pai[256]; }
    float xer = 0.5f * (zkr + zmr), xei = 0.5f * (zki - zmi);
    float dr  = 0.5f * (zkr - zmr), di  = 0.5f * (zki + zmi);
    float xor_ = di, xoi = -dr;
    float s1, c1;
    sincosf(-PI_F * k * (1.f / 512.f), &s1, &c1);
    float txr = c1 * xor_ - s1 * xoi;
    float txi = c1 * xoi + s1 * xor_;
    float Xkr = xer + txr, Xki = xei + txi;        // X[k]
    float Xmr = xer - txr, Xmi = txi - xei;        // X[512-k]
    size_t base = (size_t)m * 513;
    auto mkS = [&](int bin, float r, float i2, bool dropim, float& sr, float& si) {
        float mv = b2f(mk[base + bin]);
        float pr = r + EPSF, pi = i2 + EPSF;
        float den = sqrtf(pr * pr + pi * pi);
        float mg  = sqrtf(fmaxf(r * r + i2 * i2, EPSF));
        float amp = mv * mg * __fdividef(1.f, fmaxf(den, 1e-30f));
        sr = amp * pr; si = dropim ? 0.f : amp * pi;
    };
    float skr, ski, smr, smi;
    if (k == 0) { mkS(0, Xkr, Xki, true, skr, ski);  mkS(512, Xmr, Xmi, true, smr, smi); }
    else        { mkS(k, Xkr, Xki, false, skr, ski); mkS(512 - k, Xmr, Xmi, false, smr, smi); }
    float xe2r = 0.5f * (skr + smr), xe2i = 0.5f * (ski - smi);
    float d2r  = 0.5f * (skr - smr), d2i  = 0.5f * (ski + smi);
    float s2, c2;
    sincosf(PI_F * k * (1.f / 512.f), &s2, &c2);   // e^{+2*pi*i*k/1024}
    float o2r = c2 * d2r - s2 * d2i;
    float o2i = c2 * d2i + s2 * d2r;
    are[k] = xe2r - o2i; aim[k] = -(xe2i + o2r);
    if (k > 0) { are[512 - k] = xe2r + o2i; aim[512 - k] = xe2i - o2r; }
    else {
        float s6r, s6i; mkS(256, q2r, q2i, false, s6r, s6i);
        are[256] = s6r; aim[256] = s6i;            // conj(Z'[256]) = S256
    }
    float *p2r = are, *p2i = aim, *p2br = bre, *p2bi = bim;
    fft512core(p2r, p2i, p2br, p2bi, twr, twi, tid);
    float sc = 1.f / 512.f;
    int n = 2 * tid;
    sv4 o4;
    o4[0] = f2b(p2r[n] * sc);      o4[1] = f2b(-p2i[n] * sc);
    o4[2] = f2b(p2r[n + 1] * sc);  o4[3] = f2b(-p2i[n + 1] * sc);
    *(sv4*)(y1 + (size_t)m * 1024 + 4 * tid) = o4;
}

// ---------------- bf16 MFMA GEMM: out = act(A @ W^T + b1 + b2) [* mul], bf16 out ----------
// ACT: 0 = none, 1 = sigmoid, 2 = sigmoid then * mul(bf16)
// PERM: output column permutation gate-major -> j-major: col G stored at (G&127)*4 + (G>>7)
template<int ACT, bool PERM>
__global__ __launch_bounds__(256) void gemm_k(
    const short* __restrict__ A, int lda,
    const short* __restrict__ W, int ldw,
    short* __restrict__ outB, int ldc,
    int Mr, int Nc, int Kp,
    const float* __restrict__ b1, const float* __restrict__ b2,
    const short* __restrict__ mul, int ldm)
{
    __shared__ short As[128 * 32];
    __shared__ short Bs[128 * 32];
    int tid = threadIdx.x;
    int m0 = blockIdx.x * 128, n0 = blockIdx.y * 128;
    int w = tid >> 6, lane = tid & 63, llo = lane & 15, lhi = lane >> 4;
    int wm = w & 1, wn = w >> 1;
    fv4 acc[4][4] = {};
    int nK = Kp >> 5;
    for (int kb = 0; kb < nK; ++kb) {
        __syncthreads();
        #pragma unroll
        for (int i = 0; i < 2; ++i) {
            int idx = tid + i * 256;
            int row = idx >> 2, c = idx & 3;
            int ra = m0 + row; if (ra > Mr - 1) ra = Mr - 1;
            sv8 va = *(const sv8*)(A + (size_t)ra * lda + kb * 32 + c * 8);
            *(sv8*)&As[idx * 8] = va;
            int rb = n0 + row; if (rb > Nc - 1) rb = Nc - 1;
            sv8 vb = *(const sv8*)(W + (size_t)rb * ldw + kb * 32 + c * 8);
            *(sv8*)&Bs[idx * 8] = vb;
        }
        __syncthreads();
        sv8 af[4], bfr[4];
        #pragma unroll
        for (int mt = 0; mt < 4; ++mt) af[mt]  = *(const sv8*)&As[(wm * 64 + mt * 16 + llo) * 32 + lhi * 8];
        #pragma unroll
        for (int nt = 0; nt < 4; ++nt) bfr[nt] = *(const sv8*)&Bs[(wn * 64 + nt * 16 + llo) * 32 + lhi * 8];
        #pragma unroll
        for (int mt = 0; mt < 4; ++mt)
            #pragma unroll
            for (int nt = 0; nt < 4; ++nt)
                acc[mt][nt] = __builtin_amdgcn_mfma_f32_16x16x32_bf16(af[mt], bfr[nt], acc[mt][nt], 0, 0, 0);
    }
    #pragma unroll
    for (int nt = 0; nt < 4; ++nt) {
        int col = n0 + wn * 64 + nt * 16 + llo;
        if (col >= Nc) continue;
        float bv = 0.f;
        if (b1) bv += b1[col];
        if (b2) bv += b2[col];
        int oc = PERM ? ((col & 127) * 4 + (col >> 7)) : col;
        #pragma unroll
        for (int mt = 0; mt < 4; ++mt) {
            #pragma unroll
            for (int r = 0; r < 4; ++r) {
                int row = m0 + wm * 64 + mt * 16 + lhi * 4 + r;
                if (row >= Mr) continue;
                float v = acc[mt][nt][r] + bv;
                if constexpr (ACT >= 1) v = sigm(v);
                if constexpr (ACT == 2) v *= b2f(mul[(size_t)row * ldm + col]);
                outB[(size_t)row * ldc + oc] = f2b(v);
            }
        }
    }
}

// ---------------- LSTM scan v5: ONE barrier/step, wave-local gate redistribution ----------
// 2 batch / block, 4 waves. Wave w owns j-range [w*32, w*32+32): 8 MFMA tiles (Whh in VGPRs).
// After MFMA, wave w's 64 cells (2b x 32j) redistribute through wave-private LDS (gw[w])
// with only an lgkm wait (wave-synchronous, NO barrier). Gates run on all 64 lanes
// (1 cell/lane, c-state per-lane). Single block barrier/step publishes h for next matvec.
// Per-step barriers are LDS-only (prefetch/flush stay in flight); bar_all once per chunk.
__global__ __launch_bounds__(256, 1) void scan_k(const short* __restrict__ xg,
                                                 const float* __restrict__ Whh,
                                                 short* __restrict__ Hout) {
    __shared__ short stage[2][2 * STG * 512];  // xg: [buf][b*16+tr][j*4+g], 32 KB each
    __shared__ short hl[16 * 132];             // h rows (A-frag layout, rows 2..15 stay 0)
    __shared__ short hbuf[STG * 256];          // h history: [tr][b][j]
    __shared__ float gw[4][64 * 4];            // per-wave gate scratch: [cell][4]
    int tid = threadIdx.x;
    int lane = tid & 63, w = tid >> 6, llo = lane & 15, lhi = lane >> 4;
    // Whh -> B-frags: wreg[g][jj][kc]: lane holds Whh[g*128 + w*32 + jj*16 + llo][kc*32+lhi*8 ..+8]
    sv8 wreg[4][2][4];
    #pragma unroll
    for (int g = 0; g < 4; ++g)
        #pragma unroll
        for (int jj = 0; jj < 2; ++jj) {
            int gate = g * 128 + w * 32 + jj * 16 + llo;
            #pragma unroll
            for (int kc = 0; kc < 4; ++kc) {
                const float* src = Whh + (size_t)gate * 128 + kc * 32 + lhi * 8;
                sv8 v;
                #pragma unroll
                for (int e = 0; e < 8; ++e) v[e] = f2b(src[e]);
                wreg[g][jj][kc] = v;
            }
        }
    for (int i = tid; i < 16 * 132; i += 256) hl[i] = 0;
    int b0 = blockIdx.x * 2;
    const short* xgb = xg + ((size_t)b0 * T_N) * 512;
    short* hob = Hout + ((size_t)b0 * T_N) * 128;
    float cst = 0.f;                           // cell state: lane cell = (b=lane>>5, j=w*32+(lane&31))
    int cbb = lane >> 5, cjr = lane & 31, cj = w * 32 + cjr;
    auto prefetch = [&](int t0n, short* buf) {
        #pragma unroll
        for (int it = 0; it < 8; ++it) {
            int row = w * 8 + it;              // row = b*16 + tr
            int bb = row >> 4;
            int tg = t0n + (row & 15); if (tg > T_N - 1) tg = T_N - 1;
            const short* src = xgb + ((size_t)bb * T_N + tg) * 512 + lane * 8;
            async_ld16(src, buf + row * 512);
        }
    };
    auto flushf = [&](int tbase, int ns2) {    // hbuf -> Hout, coalesced b128 (512 x 16B)
        #pragma unroll
        for (int half = 0; half < 2; ++half) {
            int r = half * 256 + tid;
            int tr2 = r >> 5, fb = (r >> 4) & 1, j8 = r & 15;
            if (tr2 < ns2) {
                sv8 v = *(const sv8*)&hbuf[r * 8];
                *(sv8*)(hob + ((size_t)fb * T_N + tbase + tr2) * 128 + j8 * 8) = v;
            }
        }
    };
    prefetch(0, stage[0]);
    __syncthreads();                           // inits visible + stage[0] ready (vm drained)
    for (int t0 = 0; t0 < T_N; t0 += STG) {
        int cb = (t0 / STG) & 1;
        short* buf = stage[cb];
        if (t0 + STG < T_N) prefetch(t0 + STG, stage[cb ^ 1]);
        int ns = (T_N - t0 < STG) ? (T_N - t0) : STG;
        for (int tr = 0; tr < ns; ++tr) {
            // ---- matvec: h(t-1) @ Whh^T ----
            sv8 af[4];
            #pragma unroll
            for (int kc = 0; kc < 4; ++kc)
                af[kc] = *(const sv8*)&hl[llo * 132 + kc * 32 + lhi * 8];
            fv4 acc[4][2];
            #pragma unroll
            for (int g = 0; g < 4; ++g)
                #pragma unroll
                for (int jj = 0; jj < 2; ++jj) {
                    fv4 a = {0.f, 0.f, 0.f, 0.f};
                    #pragma unroll
                    for (int kc = 0; kc < 4; ++kc)
                        a = __builtin_amdgcn_mfma_f32_16x16x32_bf16(af[kc], wreg[g][jj][kc], a, 0, 0, 0);
                    acc[g][jj] = a;
                }
            // ---- wave-local redistribute: lanes lhi==0 hold rows 0,1 (= batches) ----
            if (lhi == 0) {
                #pragma unroll
                for (int jj = 0; jj < 2; ++jj)
                    #pragma unroll
                    for (int r = 0; r < 2; ++r) {
                        int cell = r * 32 + jj * 16 + llo;      // b*32 + jrel
                        fv4 pk = { acc[0][jj][r], acc[1][jj][r], acc[2][jj][r], acc[3][jj][r] };
                        *(fv4*)&gw[w][cell * 4] = pk;
                    }
            }
            wave_lds_fence();                  // same-wave producer->consumer, no barrier
            // ---- gates: all 64 lanes, 1 cell each ----
            {
                fv4 pre = *(const fv4*)&gw[w][(cbb * 32 + cjr) * 4];
                sv4 xs = *(const sv4*)&buf[(cbb * 16 + tr) * 512 + cj * 4];
                float gi = pre[0] + b2f(xs[0]);
                float gf = pre[1] + b2f(xs[1]);
                float gg = pre[2] + b2f(xs[2]);
                float go = pre[3] + b2f(xs[3]);
                float cn = sigm(gf) * cst + sigm(gi) * tanhf_(gg);
                float hn = sigm(go) * tanhf_(cn);
                cst = cn;
                short hb = f2b(hn);
                hl[cbb * 132 + cj] = hb;
                hbuf[tr * 256 + cbb * 128 + cj] = hb;
            }
            bar_lds();                         // publish h to all waves; LDS-only
        }
        flushf(t0, ns);
        bar_all();                             // next stage ready; flush ordered vs hbuf reuse
    }
}

// ---------------- instance layer norm over last dim (256), bf16 in/out ----------------
__global__ __launch_bounds__(256) void iln_k(const short* __restrict__ enc,
                                             const float* __restrict__ gamma, const float* __restrict__ beta,
                                             short* __restrict__ out, int Mr) {
    int tid = threadIdx.x;
    int lane = tid & 63;
    int row = blockIdx.x * 4 + (tid >> 6);
    if (row >= Mr) return;
    sv4 v4 = *(const sv4*)(enc + (size_t)row * 256 + lane * 4);
    float vx = b2f(v4[0]), vy = b2f(v4[1]), vz = b2f(v4[2]), vw = b2f(v4[3]);
    float s = vx + vy + vz + vw;
    #pragma unroll
    for (int o = 32; o; o >>= 1) s += __shfl_xor(s, o);
    float mean = s * (1.f / 256.f);
    float dx = vx - mean, dy = vy - mean, dz = vz - mean, dw = vw - mean;
    float q = dx * dx + dy * dy + dz * dz + dw * dw;
    #pragma unroll
    for (int o = 32; o; o >>= 1) q += __shfl_xor(q, o);
    float rs = rsqrtf(q * (1.f / 256.f) + 1e-7f);
    float4 g = ((const float4*)gamma)[lane];
    float4 b = ((const float4*)beta)[lane];
    sv4 o4;
    o4[0] = f2b(dx * rs * g.x + b.x);
    o4[1] = f2b(dy * rs * g.y + b.y);
    o4[2] = f2b(dz * rs * g.z + b.z);
    o4[3] = f2b(dw * rs * g.w + b.w);
    *(sv4*)(out + (size_t)row * 256 + lane * 4) = o4;
}

// ---------------- overlap-add (dec bf16 -> out fp32) ----------------
__global__ __launch_bounds__(256) void ola_k(const short* __restrict__ dec, float* __restrict__ out, int n) {
    int gid = blockIdx.x * 256 + threadIdx.x;
    if (gid >= n) return;
    int b = gid / NS_N;
    int s = gid - b * NS_N;
    int thi = s >> 8; if (thi > T_N - 1) thi = T_N - 1;
    int tlo = (s >= 1023) ? ((s - 1023 + 255) >> 8) : 0;
    float acc = 0.f;
    for (int t2 = tlo; t2 <= thi; ++t2)
        acc += b2f(dec[(size_t)(b * T_N + t2) * 1024 + (s - (t2 << 8))]);
    out[gid] = acc;
}

extern "C" void kernel_launch(void* const* d_in, const int* in_sizes, int n_in,
                              void* d_out, int out_size, void* d_ws, size_t ws_size,
                              hipStream_t stream) {
    (void)in_sizes; (void)n_in; (void)out_size;
    const float* x      = (const float*)d_in[0];
    const float* s1Wih1 = (const float*)d_in[3];
    const float* s1Whh1 = (const float*)d_in[4];
    const float* s1bih1 = (const float*)d_in[5];
    const float* s1bhh1 = (const float*)d_in[6];
    const float* s1Wih2 = (const float*)d_in[7];
    const float* s1Whh2 = (const float*)d_in[8];
    const float* s1bih2 = (const float*)d_in[9];
    const float* s1bhh2 = (const float*)d_in[10];
    const float* s1Wd   = (const float*)d_in[11];
    const float* s1bd   = (const float*)d_in[12];
    const float* s2Wih1 = (const float*)d_in[13];
    const float* s2Whh1 = (const float*)d_in[14];
    const float* s2bih1 = (const float*)d_in[15];
    const float* s2bhh1 = (const float*)d_in[16];
    const float* s2Wih2 = (const float*)d_in[17];
    const float* s2Whh2 = (const float*)d_in[18];
    const float* s2bih2 = (const float*)d_in[19];
    const float* s2bhh2 = (const float*)d_in[20];
    const float* s2Wd   = (const float*)d_in[21];
    const float* s2bd   = (const float*)d_in[22];
    const float* encW   = (const float*)d_in[23];
    const float* decW   = (const float*)d_in[24];
    const float* gamma  = (const float*)d_in[25];
    const float* beta   = (const float*)d_in[26];
    float* out = (float*)d_out;

    char* ws = (char*)d_ws;
    size_t off = 0;
    auto alloc = [&](size_t bytes) -> void* {
        size_t o = (off + 255) & ~(size_t)255;
        off = o + bytes;
        return (void*)(ws + o);
    };
    // persistent weights (converted once per launch)
    short* Wih1p = (short*)alloc((size_t)512 * 544 * 2);
    short* Wih2a = (short*)alloc((size_t)512 * 128 * 2);
    short* Wd1   = (short*)alloc((size_t)513 * 128 * 2);
    short* Wih1b = (short*)alloc((size_t)512 * 256 * 2);
    short* Wih2b = (short*)alloc((size_t)512 * 128 * 2);
    short* Wd2   = (short*)alloc((size_t)256 * 128 * 2);
    short* encWb = (short*)alloc((size_t)256 * 1024 * 2);
    short* decWb = (short*)alloc((size_t)1024 * 256 * 2);
    size_t woff = off;

    // choose the largest even batch-chunk MB whose buffers fit ws_size
    int MB = 0;
    for (int mb = 64; mb >= 2; mb -= 2) {
        size_t Mc = (size_t)mb * T_N;
        size_t tot = woff;
        auto add = [&](size_t bts) { tot = ((tot + 255) & ~(size_t)255) + bts; };
        add(Mc * 1056 * 2);  // R1 (mag 544 | xg 512; y1/dec alias)
        add(Mc * 128 * 2);   // H1
        add(Mc * 128 * 2);   // H2
        add(Mc * 513 * 2);   // Rm (mask1; encn/adec alias)
        add(Mc * 256 * 2);   // encb
        if (tot <= ws_size) { MB = mb; break; }
    }
    if (MB == 0) return;  // hopeless: < ~11 MB of scratch
    size_t McCap = (size_t)MB * T_N;
    short* R1   = (short*)alloc(McCap * 1056 * 2);
    short* H1   = (short*)alloc(McCap * 128 * 2);
    short* H2   = (short*)alloc(McCap * 128 * 2);
    short* Rm   = (short*)alloc(McCap * 513 * 2);
    short* encb = (short*)alloc(McCap * 256 * 2);

    // weight conversions (fp32 -> bf16, K zero-padded)
    wcvt_k<<<dim3(3, 512),  256, 0, stream>>>(s1Wih1, Wih1p, 513, 544);
    wcvt_k<<<dim3(1, 512),  256, 0, stream>>>(s1Wih2, Wih2a, 128, 128);
    wcvt_k<<<dim3(1, 513),  256, 0, stream>>>(s1Wd,   Wd1,   128, 128);
    wcvt_k<<<dim3(1, 512),  256, 0, stream>>>(s2Wih1, Wih1b, 256, 256);
    wcvt_k<<<dim3(1, 512),  256, 0, stream>>>(s2Wih2, Wih2b, 128, 128);
    wcvt_k<<<dim3(1, 256),  256, 0, stream>>>(s2Wd,   Wd2,   128, 128);
    wcvt_k<<<dim3(4, 256),  256, 0, stream>>>(encW,   encWb, 1024, 1024);
    wcvt_k<<<dim3(1, 1024), 256, 0, stream>>>(decW,   decWb, 256, 256);

    for (int cs = 0; cs < B_N; cs += MB) {
        int mb = (B_N - cs < MB) ? (B_N - cs) : MB;
        size_t mc = (size_t)mb * T_N;
        int gx = (int)((mc + 127) / 128);
        const float* xc = x + (size_t)cs * NS_N;
        float* outc = out + (size_t)cs * NS_N;
        short* mag  = R1;
        short* xg   = R1 + mc * 544;
        short* y1   = R1;             // alias (mag+xg dead)
        short* decb = R1;             // alias (y1/xg dead)
        short* mask1 = Rm;
        short* encn  = Rm;            // alias (mask1 dead)
        short* adec  = Rm + mc * 256; // alias (mask1 dead)

        // STFT magnitudes
        fft_fwd_k<<<(int)mc, 256, 0, stream>>>(xc, mag);
        // separation block 1 (xg gemms emit j-major layout for the scan)
        gemm_k<0, true><<<dim3(gx, 4), 256, 0, stream>>>(mag, 544, Wih1p, 544, xg, 512, (int)mc, 512, 544, s1bih1, s1bhh1, nullptr, 0);
        scan_k<<<mb / 2, 256, 0, stream>>>(xg, s1Whh1, H1);
        gemm_k<0, true><<<dim3(gx, 4), 256, 0, stream>>>(H1, 128, Wih2a, 128, xg, 512, (int)mc, 512, 128, s1bih2, s1bhh2, nullptr, 0);
        scan_k<<<mb / 2, 256, 0, stream>>>(xg, s1Whh2, H2);
        gemm_k<1, false><<<dim3(gx, 5), 256, 0, stream>>>(H2, 128, Wd1, 128, mask1, 513, (int)mc, 513, 128, s1bd, nullptr, nullptr, 0);
        // masked iSTFT + encoder + norm
        ifft_k<<<(int)mc, 256, 0, stream>>>(xc, mask1, y1);
        gemm_k<0, false><<<dim3(gx, 2), 256, 0, stream>>>(y1, 1024, encWb, 1024, encb, 256, (int)mc, 256, 1024, nullptr, nullptr, nullptr, 0);
        iln_k<<<(int)((mc + 3) / 4), 256, 0, stream>>>(encb, gamma, beta, encn, (int)mc);
        // separation block 2
        gemm_k<0, true><<<dim3(gx, 4), 256, 0, stream>>>(encn, 256, Wih1b, 256, xg, 512, (int)mc, 512, 256, s2bih1, s2bhh1, nullptr, 0);
        scan_k<<<mb / 2, 256, 0, stream>>>(xg, s2Whh1, H1);
        gemm_k<0, true><<<dim3(gx, 4), 256, 0, stream>>>(H1, 128, Wih2b, 128, xg, 512, (int)mc, 512, 128, s2bih2, s2bhh2, nullptr, 0);
        scan_k<<<mb / 2, 256, 0, stream>>>(xg, s2Whh2, H2);
        gemm_k<2, false><<<dim3(gx, 2), 256, 0, stream>>>(H2, 128, Wd2, 128, adec, 256, (int)mc, 256, 128, s2bd, nullptr, encb, 256);
        // decoder + overlap-add
        gemm_k<0, false><<<dim3(gx, 8), 256, 0, stream>>>(adec, 256, decWb, 256, decb, 1024, (int)mc, 1024, 256, nullptr, nullptr, nullptr, 0);
        ola_k<<<mb * 1000, 256, 0, stream>>>(decb, outc, mb * NS_N);
    }
}